// Round 10
// baseline (290.855 us; speedup 1.0000x reference)
//
#include <hip/hip_runtime.h>

typedef _Float16 half_t;
typedef _Float16 half8 __attribute__((ext_vector_type(8)));
typedef float f32x4 __attribute__((ext_vector_type(4)));

#define D_EMBED   1024
#define D_CROSS   768
#define N_HEADS   8
#define D_HEAD    128
#define BATCH     8
#define SEQ_Q     4096
#define SEQ_KV    77
#define SKV_PAD   80
#define NKV       (N_HEADS*SKV_PAD)     /* 640 */
#define M_Q       (BATCH*SEQ_Q)         /* 32768 */

// ---------------- workspace layout (bytes) ----------------
#define WS_S     ((size_t)0)                                   // S then P in-place: [32768][640] fp16 (A-swizzled)
#define WS_WQC   (WS_S    + (size_t)M_Q*NKV*2)
#define WS_WOT   (WS_WQC  + (size_t)D_EMBED*D_EMBED*2)
#define WS_WKVT  (WS_WOT  + (size_t)D_EMBED*D_EMBED*2)
#define WS_YH    (WS_WKVT + (size_t)2*D_EMBED*D_CROSS*2)
#define WS_KV    (WS_YH   + (size_t)BATCH*SKV_PAD*D_CROSS*2)
#define WS_BKV   (WS_KV   + (size_t)BATCH*SKV_PAD*2*D_EMBED*2)
#define WS_BT1   (WS_BKV  + (size_t)2*D_EMBED*4)               // W1^T fp16 [8][640][1024] (old 2-bit swz)
#define WS_BT2   (WS_BT1  + (size_t)BATCH*NKV*D_EMBED*2)       // W2^T fp16 [8][1024][640] (3-bit swz)
#define WS_C1    (WS_BT2  + (size_t)BATCH*D_EMBED*NKV*2)       // c1 fp32 [8][640]

#define ATTN_SCALE 0.08838834764831845f

__device__ __forceinline__ void gload_lds16(const void* g, void* lds) {
  __builtin_amdgcn_global_load_lds(
      (const __attribute__((address_space(1))) unsigned int*)g,
      (__attribute__((address_space(3))) unsigned int*)lds, 16, 0, 0);
}
__device__ __forceinline__ void BAR() {
  __builtin_amdgcn_s_barrier();
  __builtin_amdgcn_sched_barrier(0);
}

// ---------------- prep kernels (unchanged) ----------------
__global__ void cast_f32_f16(const float* __restrict__ src, half_t* __restrict__ dst) {
  int i = blockIdx.x * 256 + threadIdx.x;
  f32x4 a = *(const f32x4*)(src + (size_t)i*8);
  f32x4 b = *(const f32x4*)(src + (size_t)i*8 + 4);
  half8 h;
#pragma unroll
  for (int j = 0; j < 4; ++j) { h[j] = (half_t)a[j]; h[j+4] = (half_t)b[j]; }
  *(half8*)(dst + (size_t)i*8) = h;
}

__global__ void transpose_f32f16(const float* __restrict__ src, half_t* __restrict__ dst,
                                 int K, int N) {
  __shared__ float tile[32][33];
  int n0 = blockIdx.x * 32, k0 = blockIdx.y * 32;
  int tx = threadIdx.x, ty = threadIdx.y;
#pragma unroll
  for (int j = 0; j < 4; ++j)
    tile[ty + j*8][tx] = src[(size_t)(k0 + ty + j*8)*N + n0 + tx];
  __syncthreads();
#pragma unroll
  for (int j = 0; j < 4; ++j)
    dst[(size_t)(n0 + ty + j*8)*K + k0 + tx] = (half_t)tile[tx][ty + j*8];
}

__global__ void convert_pad_y(const float* __restrict__ y, half_t* __restrict__ yh) {
  int idx = blockIdx.x * 256 + threadIdx.x;
  int r = idx / D_CROSS, col = idx - r*D_CROSS;
  int b = r / SKV_PAD, s = r - b*SKV_PAD;
  yh[idx] = (s < SEQ_KV) ? (half_t)y[(size_t)(b*SEQ_KV + s)*D_CROSS + col] : (half_t)0.f;
}

__global__ void concat_bias(const float* __restrict__ bk, const float* __restrict__ bv,
                            float* __restrict__ bkv) {
  int i = blockIdx.x * 256 + threadIdx.x;
  bkv[i] = (i < D_EMBED) ? bk[i] : bv[i - D_EMBED];
}

// ---------------- 128x128 GEMM — K/V projection (R7-verified) ----------------
__global__ __launch_bounds__(256, 3)
void gemm_kv(const half_t* __restrict__ A, const half_t* __restrict__ Bt,
             const float* __restrict__ bias, half_t* __restrict__ C,
             int M, int N, int K) {
  __shared__ half_t As[3][128*32];
  __shared__ half_t Bs[2][128*32];
  const int tid = threadIdx.x;
  const int l = tid & 63, w = tid >> 6;
  const int l4 = l & 15, lh = l >> 4;
  const int bn0 = blockIdx.x * 128, bm0 = blockIdx.y * 128;
  const int wr = w >> 1, wc = w & 1;
  const int rslot = lh << 4;
  f32x4 acc[4][4] = {};
  const int nk = K >> 5;
  const int srow = w*16 + (l >> 2);
  const int scol = (l & 3)*8;

  auto stageB = [&](int kt, int bb) {
    const half_t* g = Bt + (size_t)(bn0 + srow)*K + scol + kt*32;
    gload_lds16(g,                 (char*)Bs[bb] + w*1024);
    gload_lds16(g + (size_t)64*K,  (char*)Bs[bb] + 4096 + w*1024);
  };
  auto stageA = [&](int kt, int bb) {
    const half_t* g = A + (size_t)(bm0 + srow)*K + scol + kt*32;
    gload_lds16(g,                 (char*)As[bb] + w*1024);
    gload_lds16(g + (size_t)64*K,  (char*)As[bb] + 4096 + w*1024);
  };
  auto compute = [&](int ab, int bb) {
    half8 af[4], bf[4];
#pragma unroll
    for (int m = 0; m < 4; ++m)
      af[m] = *(const half8*)((const char*)As[ab] + (size_t)(wr*64 + m*16 + l4)*64 + rslot);
#pragma unroll
    for (int n = 0; n < 4; ++n)
      bf[n] = *(const half8*)((const char*)Bs[bb] + (size_t)(wc*64 + n*16 + l4)*64 + rslot);
#pragma unroll
    for (int m = 0; m < 4; ++m)
#pragma unroll
      for (int n = 0; n < 4; ++n)
        acc[m][n] = __builtin_amdgcn_mfma_f32_16x16x32_f16(af[m], bf[n], acc[m][n], 0, 0, 0);
  };

  stageA(0, 0); stageA(1, 1); stageB(0, 0);
  asm volatile("s_waitcnt vmcnt(0)" ::: "memory");
  BAR();
  int aCur = 0, aP2 = 2;
  for (int t = 0; t < nk; ++t) {
    if (t + 1 < nk) stageB(t + 1, (t + 1) & 1);
    if (t + 2 < nk) stageA(t + 2, aP2);
    compute(aCur, t & 1);
    if (t + 1 < nk) {
      if (t + 2 < nk) { asm volatile("s_waitcnt vmcnt(2)" ::: "memory"); }
      else            { asm volatile("s_waitcnt vmcnt(0)" ::: "memory"); }
      BAR();
    }
    aCur = (aCur == 2) ? 0 : aCur + 1;
    aP2  = (aP2  == 2) ? 0 : aP2  + 1;
  }

  const int cb = bn0 + wc*64, rb = bm0 + wr*64;
#pragma unroll
  for (int n = 0; n < 4; ++n) {
    const int col = cb + n*16 + l4;
    const float bvv = bias[col];
#pragma unroll
    for (int m = 0; m < 4; ++m)
#pragma unroll
      for (int j = 0; j < 4; ++j)
        C[(size_t)(rb + m*16 + lh*4 + j)*N + col] = (half_t)(acc[m][n][j] + bvv);
  }
}

// ---------------- builders ----------------
// Bt1 (old 2-bit swizzle, matches gemm_bt's B-read) — unchanged
__global__ __launch_bounds__(256, 2)
void w1_build(const half_t* __restrict__ kvb, const half_t* __restrict__ Wqc,
              half_t* __restrict__ Bt1) {
  __shared__ half_t K_lds[80*136];
  const int blk = blockIdx.x;
  const int b = blk >> 3, h = blk & 7;
  const int tid = threadIdx.x;
  const int l = tid & 63, w = tid >> 6;
  const int l4 = l & 15, lh = l >> 4;
  for (int i = tid; i < 80*16; i += 256) {
    int s = i >> 4, d = (i & 15) << 3;
    *(half8*)(K_lds + s*136 + d) =
        *(const half8*)(kvb + (size_t)(b*SKV_PAD + s)*2048 + h*128 + d);
  }
  __syncthreads();
  for (int c = 0; c < 4; ++c) {
    f32x4 acc[5][4] = {};
#pragma unroll
    for (int kt = 0; kt < 4; ++kt) {
      half8 af[5], bf[4];
#pragma unroll
      for (int m = 0; m < 5; ++m)
        af[m] = *(const half8*)(K_lds + (size_t)(m*16 + l4)*136 + kt*32 + lh*8);
#pragma unroll
      for (int n = 0; n < 4; ++n)
        bf[n] = *(const half8*)(Wqc + (size_t)(w*256 + c*64 + n*16 + l4)*1024 + h*128 + kt*32 + lh*8);
#pragma unroll
      for (int m = 0; m < 5; ++m)
#pragma unroll
        for (int n = 0; n < 4; ++n)
          acc[m][n] = __builtin_amdgcn_mfma_f32_16x16x32_f16(af[m], bf[n], acc[m][n], 0, 0, 0);
    }
#pragma unroll
    for (int n = 0; n < 4; ++n) {
      const int colk = w*256 + c*64 + n*16 + l4;
#pragma unroll
      for (int m = 0; m < 5; ++m)
#pragma unroll
        for (int j = 0; j < 4; ++j) {
          const int srow = m*16 + lh*4 + j;
          size_t byte = (((size_t)(b*NKV + h*SKV_PAD + srow))*1024 + colk)*2;
          byte ^= ((size_t)((srow >> 1) & 3)) << 4;
          *(half_t*)((char*)Bt1 + byte) = (half_t)(acc[m][n][j]*ATTN_SCALE);
        }
    }
  }
}

// Bt2 with 3-bit A/B-swizzle: within each 128B K-group, slot ^= (nrow&7)
__global__ __launch_bounds__(256, 2)
void w2_build(const half_t* __restrict__ kvb, const half_t* __restrict__ Wot,
              half_t* __restrict__ Bt2) {
  __shared__ half_t V_lds[80*136];
  const int blk = blockIdx.x;
  const int b = blk >> 3, h = blk & 7;
  const int tid = threadIdx.x;
  const int l = tid & 63, w = tid >> 6;
  const int l4 = l & 15, lh = l >> 4;
  for (int i = tid; i < 80*16; i += 256) {
    int s = i >> 4, d = (i & 15) << 3;
    *(half8*)(V_lds + s*136 + d) =
        *(const half8*)(kvb + (size_t)(b*SKV_PAD + s)*2048 + 1024 + h*128 + d);
  }
  __syncthreads();
  for (int c = 0; c < 4; ++c) {
    f32x4 acc[4][5] = {};
#pragma unroll
    for (int kt = 0; kt < 4; ++kt) {
      half8 af[4], bf[5];
#pragma unroll
      for (int m = 0; m < 4; ++m)
        af[m] = *(const half8*)(Wot + (size_t)(w*256 + c*64 + m*16 + l4)*1024 + h*128 + kt*32 + lh*8);
#pragma unroll
      for (int n = 0; n < 5; ++n)
        bf[n] = *(const half8*)(V_lds + (size_t)(n*16 + l4)*136 + kt*32 + lh*8);
#pragma unroll
      for (int m = 0; m < 4; ++m)
#pragma unroll
        for (int n = 0; n < 5; ++n)
          acc[m][n] = __builtin_amdgcn_mfma_f32_16x16x32_f16(af[m], bf[n], acc[m][n], 0, 0, 0);
    }
#pragma unroll
    for (int m = 0; m < 4; ++m) {
#pragma unroll
      for (int j = 0; j < 4; ++j) {
        const int nrow = w*256 + c*64 + m*16 + lh*4 + j;
        const size_t rowbase = ((size_t)(b*1024 + nrow))*1280;
#pragma unroll
        for (int n = 0; n < 5; ++n) {
          const int cc = h*80 + n*16 + l4;          // 0..639
          size_t byte = rowbase + (size_t)(cc >> 6)*128
                        + ((size_t)(((cc >> 3) & 7) ^ (nrow & 7)) << 4) + ((cc & 7) << 1);
          *(half_t*)((char*)Bt2 + byte) = (half_t)acc[m][n][j];
        }
      }
    }
  }
}

__global__ void c1_build(const half_t* __restrict__ kvb, const float* __restrict__ bq,
                         float* __restrict__ c1) {
  int idx = blockIdx.x * 256 + threadIdx.x;
  int b = idx / NKV, n = idx - b*NKV;
  int h = n / SKV_PAD, s = n - h*SKV_PAD;
  const half_t* kp = kvb + (size_t)(b*SKV_PAD + s)*2048 + h*128;
  float acc = 0.f;
#pragma unroll 8
  for (int d = 0; d < 128; ++d) acc += bq[h*128 + d] * (float)kp[d];
  c1[idx] = acc * ATTN_SCALE;
}

// ---------------- S-GEMM (unchanged structure; epilogue stores S A-swizzled) ----------------
template<int NBX>
__global__ __launch_bounds__(256, 3)
void gemm_s(const float* __restrict__ Av, const half_t* __restrict__ BtAll,
            const float* __restrict__ biasAll, half_t* __restrict__ Cv,
            int M, int N, int K) {
  __shared__ half_t As[2][128*32];
  __shared__ half_t Bs[3][128*32];
  const int tid = threadIdx.x;
  const int l  = tid & 63;
  const int w  = tid >> 6;
  const int l4 = l & 15, lh = l >> 4;

  const int chunk = (int)gridDim.x >> 3;
  const int sb = blockIdx.x;
  const int lin = (sb & 7)*chunk + (sb >> 3);
  const int bx = lin % NBX;
  const int by = lin / NBX;
  const int b  = by >> 5;
  const half_t* Bt  = BtAll  + (size_t)b*NKV*1024;
  const float* bias = biasAll + (size_t)b*NKV;

  const int bn0 = bx * 128;
  const int bm0 = by * 128;
  const int wr = w >> 1, wc = w & 1;
  const int aslot = lh << 4;
  const int bslot = (lh ^ ((l4 >> 1) & 3)) << 4;

  f32x4 acc[4][4] = {};
  const int nk = K >> 5;
  const int srow = w*16 + (l >> 2);
  const int scol = (l & 3)*8;

  auto stageB = [&](int kt, int bb) {
    const half_t* g = Bt + (size_t)(bn0 + srow)*K + scol + kt*32;
    gload_lds16(g,                (char*)Bs[bb] + w*1024);
    gload_lds16(g + (size_t)64*K, (char*)Bs[bb] + 4096 + w*1024);
  };

  f32x4 L0, L1, L2, L3;
  const int arow = tid >> 2;
  const int ac0  = (tid & 3) * 8;
  const int wslot = (tid & 3) << 4;
  auto aload = [&](int kt) {
    const float* g0 = Av + (size_t)(bm0 + arow)*K + kt*32 + ac0;
    const float* g1 = Av + (size_t)(bm0 + 64 + arow)*K + kt*32 + ac0;
    L0 = *(const f32x4*)g0; L1 = *(const f32x4*)(g0 + 4);
    L2 = *(const f32x4*)g1; L3 = *(const f32x4*)(g1 + 4);
  };
  auto awrite = [&](int bb) {
    half8 h0, h1;
#pragma unroll
    for (int j = 0; j < 4; ++j) { h0[j] = (half_t)L0[j]; h0[j+4] = (half_t)L1[j]; }
#pragma unroll
    for (int j = 0; j < 4; ++j) { h1[j] = (half_t)L2[j]; h1[j+4] = (half_t)L3[j]; }
    *(half8*)((char*)As[bb] + (size_t)arow*64 + wslot)        = h0;
    *(half8*)((char*)As[bb] + (size_t)(64 + arow)*64 + wslot) = h1;
  };

  auto compute = [&](int ab, int bb) {
    half8 af[4], bf[4];
#pragma unroll
    for (int m = 0; m < 4; ++m)
      af[m] = *(const half8*)((const char*)As[ab] + (size_t)(wr*64 + m*16 + l4)*64 + aslot);
#pragma unroll
    for (int n = 0; n < 4; ++n)
      bf[n] = *(const half8*)((const char*)Bs[bb] + (size_t)(wc*64 + n*16 + l4)*64 + bslot);
#pragma unroll
    for (int m = 0; m < 4; ++m)
#pragma unroll
      for (int n = 0; n < 4; ++n)
        acc[m][n] = __builtin_amdgcn_mfma_f32_16x16x32_f16(af[m], bf[n], acc[m][n], 0, 0, 0);
  };

  aload(0); stageB(0, 0); stageB(1, 1);
  awrite(0);
  asm volatile("s_waitcnt vmcnt(2) lgkmcnt(0)" ::: "memory");
  BAR();
  int bCur = 0, bP2 = 2;
  for (int t = 0; t < nk; ++t) {
    if (t + 1 < nk) aload(t + 1);
    if (t + 2 < nk) stageB(t + 2, bP2);
    compute(t & 1, bCur);
    if (t + 1 < nk) {
      awrite((t + 1) & 1);
      asm volatile("s_waitcnt lgkmcnt(0)" ::: "memory");
      BAR();
    }
    bCur = (bCur == 2) ? 0 : bCur + 1;
    bP2  = (bP2  == 2) ? 0 : bP2  + 1;
  }

  // epilogue: store S with the 3-bit A-swizzle (slot ^= row&7 within 128B groups)
  const int c_base = bn0 + wc*64;
  const int r_base = bm0 + wr*64;
#pragma unroll
  for (int n = 0; n < 4; ++n) {
    const int col = c_base + n*16 + l4;
    const float bvv = bias[col];
#pragma unroll
    for (int m = 0; m < 4; ++m) {
#pragma unroll
      for (int j = 0; j < 4; ++j) {
        const int row = r_base + m*16 + lh*4 + j;
        const float v = acc[m][n][j] + bvv;
        size_t byte = (size_t)row*1280 + (size_t)(col >> 6)*128
                      + ((size_t)(((col >> 3) & 7) ^ (row & 7)) << 4) + ((col & 7) << 1);
        *(half_t*)((char*)Cv + byte) = (half_t)v;
      }
    }
  }
}

// ---------------- softmax in place over swizzled S ----------------
__global__ __launch_bounds__(256, 4)
void softmax_inplace(half_t* __restrict__ S) {
  const int gid = blockIdx.x * 256 + threadIdx.x;   // 32768*8
  const int row = gid >> 3, h = gid & 7;
  const int key = row & 7;
  char* base = (char*)S + (size_t)row*1280;
  size_t off[10];
  half8 v[10];
#pragma unroll
  for (int i = 0; i < 10; ++i) {
    const int ls = h*10 + i;
    off[i] = (size_t)(ls >> 3)*128 + ((size_t)((ls & 7) ^ key) << 4);
    v[i] = *(const half8*)(base + off[i]);
  }
  float mx = -1e30f;
#pragma unroll
  for (int i = 0; i < 10; ++i)
#pragma unroll
    for (int j = 0; j < 8; ++j)
      if (i*8 + j < SEQ_KV) mx = fmaxf(mx, (float)v[i][j]);
  float sm = 0.f;
#pragma unroll
  for (int i = 0; i < 10; ++i) {
    half8 t = v[i];
#pragma unroll
    for (int j = 0; j < 8; ++j) {
      float e = (i*8 + j < SEQ_KV) ? __expf((float)t[j] - mx) : 0.f;
      sm += e; t[j] = (half_t)e;
    }
    v[i] = t;
  }
  const float inv = 1.f / sm;
#pragma unroll
  for (int i = 0; i < 10; ++i) {
    half8 t = v[i];
#pragma unroll
    for (int j = 0; j < 8; ++j) t[j] = (half_t)((float)t[j] * inv);
    *(half8*)(base + off[i]) = t;
  }
}

// ---------------- out-GEMM: 256x256, 8 waves, 8-phase counted-vmcnt (m201 template) ----------------
// out[32768,1024] = P[32768,640(swz)] @ Bt2_b[1024,640(swz)]^T + bo. K=640 -> 5 iters of 2 K-tiles(64).
// LDS 128KB: 2 dbuf x (A 256x64 + B 256x64). vmcnt(4) at phases 4/8 only (ledger: 12 outstanding, drain 8).
#define PH8(Q, ABASE, PRE, TAIL)                                                                     \
  {                                                                                                  \
    half8 a00 = *(const half8*)((ABASE) + (size_t)(arow0 + (2*(Q)  )*16)*128 + ak0);                 \
    half8 a01 = *(const half8*)((ABASE) + (size_t)(arow0 + (2*(Q)  )*16)*128 + ak1);                 \
    half8 a10 = *(const half8*)((ABASE) + (size_t)(arow0 + (2*(Q)+1)*16)*128 + ak0);                 \
    half8 a11 = *(const half8*)((ABASE) + (size_t)(arow0 + (2*(Q)+1)*16)*128 + ak1);                 \
    PRE;                                                                                             \
    __builtin_amdgcn_s_barrier();                                                                    \
    asm volatile("s_waitcnt lgkmcnt(0)" ::: "memory");                                               \
    __builtin_amdgcn_sched_barrier(0);                                                               \
    __builtin_amdgcn_s_setprio(1);                                                                   \
    _Pragma("unroll")                                                                                \
    for (int ni = 0; ni < 4; ++ni) {                                                                 \
      acc[2*(Q)  ][ni] = __builtin_amdgcn_mfma_f32_16x16x32_f16(a00, bf[ni][0], acc[2*(Q)  ][ni],0,0,0); \
      acc[2*(Q)  ][ni] = __builtin_amdgcn_mfma_f32_16x16x32_f16(a01, bf[ni][1], acc[2*(Q)  ][ni],0,0,0); \
      acc[2*(Q)+1][ni] = __builtin_amdgcn_mfma_f32_16x16x32_f16(a10, bf[ni][0], acc[2*(Q)+1][ni],0,0,0); \
      acc[2*(Q)+1][ni] = __builtin_amdgcn_mfma_f32_16x16x32_f16(a11, bf[ni][1], acc[2*(Q)+1][ni],0,0,0); \
    }                                                                                                \
    __builtin_amdgcn_s_setprio(0);                                                                   \
    TAIL;                                                                                            \
    __builtin_amdgcn_s_barrier();                                                                    \
    __builtin_amdgcn_sched_barrier(0);                                                               \
  }

__global__ __launch_bounds__(512, 1)
void gemm8p_out(const half_t* __restrict__ Sa, const half_t* __restrict__ Bt2,
                const float* __restrict__ bo, float* __restrict__ out) {
  __shared__ half_t AbS[2*256*64];
  __shared__ half_t BbS[2*256*64];
  char* ABp = (char*)AbS;
  char* BBp = (char*)BbS;
  const int tid = threadIdx.x;
  const int l = tid & 63, w = tid >> 6;
  const int l4 = l & 15, lh = l >> 4;
  // XCD chunk=64 = one batch (4 bx x 16 by)
  const int lin = ((int)blockIdx.x & 7)*64 + ((int)blockIdx.x >> 3);
  const int bx = lin & 3, by = lin >> 2;
  const int bm0 = by << 8, bn0 = bx << 8;
  const half_t* Bt = Bt2 + (size_t)(by >> 4)*1024*640;
  const int wr = w >> 2, wc = w & 3;
  const int ak0 = ((lh    ) ^ (l4 & 7)) << 4;
  const int ak1 = ((lh + 4) ^ (l4 & 7)) << 4;
  const int arow0 = wr*128 + l4;
  const int brow0 = wc*64 + l4;
  f32x4 acc[8][4] = {};
  half8 bf[4][2];

  auto stA = [&](int kt, int db, int hf) {
#pragma unroll
    for (int r = 0; r < 2; ++r) {
      const int id = tid + r*512;
      gload_lds16((const char*)Sa + (size_t)(bm0 + hf*128 + (id >> 3))*1280 + (size_t)kt*128 + (id & 7)*16,
                  ABp + db*32768 + hf*16384 + r*8192 + w*1024);
    }
  };
  auto stB = [&](int kt, int db, int hf) {
#pragma unroll
    for (int r = 0; r < 2; ++r) {
      const int id = tid + r*512;
      gload_lds16((const char*)Bt + (size_t)(bn0 + hf*128 + (id >> 3))*1280 + (size_t)kt*128 + (id & 7)*16,
                  BBp + db*32768 + hf*16384 + r*8192 + w*1024);
    }
  };
  auto rdB = [&](const char* base) {
#pragma unroll
    for (int ni = 0; ni < 4; ++ni) {
      bf[ni][0] = *(const half8*)(base + (size_t)(brow0 + ni*16)*128 + ak0);
      bf[ni][1] = *(const half8*)(base + (size_t)(brow0 + ni*16)*128 + ak1);
    }
  };

  // prologue: A(kt0)->buf0, B(kt0)->buf0, B(kt1)->buf1; drain A0,B0; B1 stays in flight
  stA(0, 0, 0); stA(0, 0, 1); stB(0, 0, 0); stB(0, 0, 1); stB(1, 1, 0); stB(1, 1, 1);
  asm volatile("s_waitcnt vmcnt(4)" ::: "memory");
  __builtin_amdgcn_sched_barrier(0);
  __builtin_amdgcn_s_barrier();

  const char* A0 = ABp;            const char* A1 = ABp + 32768;
  const char* B0 = BBp;            const char* B1 = BBp + 32768;

  for (int u = 0; u < 5; ++u) {
    const int kt0 = 2*u, kt1 = 2*u + 1;
    const bool nx = (u < 4);
    // ---- K-tile kt0 (bufs 0) ----
    PH8(0, A0, { rdB(B0); stA(kt1, 1, 0); stA(kt1, 1, 1); }, {});
    PH8(1, A0, { if (nx) stB(kt0 + 2, 0, 0); }, {});
    PH8(2, A0, { if (nx) stB(kt0 + 2, 0, 1); }, {});
    PH8(3, A0, {}, {
      if (nx) { asm volatile("s_waitcnt vmcnt(4)" ::: "memory"); }
      else    { asm volatile("s_waitcnt vmcnt(0)" ::: "memory"); }
      __builtin_amdgcn_sched_barrier(0);
    });
    // ---- K-tile kt1 (bufs 1) ----
    PH8(0, A1, { rdB(B1); if (nx) stA(kt0 + 2, 0, 0); }, {});
    PH8(1, A1, { if (nx) stA(kt0 + 2, 0, 1); }, {});
    PH8(2, A1, { if (nx) stB(kt1 + 2, 1, 0); }, {});
    PH8(3, A1, { if (nx) stB(kt1 + 2, 1, 1); }, {
      if (nx) {
        asm volatile("s_waitcnt vmcnt(4)" ::: "memory");
        __builtin_amdgcn_sched_barrier(0);
      }
    });
  }

  // epilogue
#pragma unroll
  for (int ni = 0; ni < 4; ++ni) {
    const int col = bn0 + wc*64 + ni*16 + l4;
    const float bvv = bo[col];
#pragma unroll
    for (int mi = 0; mi < 8; ++mi)
#pragma unroll
      for (int j = 0; j < 4; ++j) {
        const int row = bm0 + wr*128 + mi*16 + lh*4 + j;
        out[(size_t)row*1024 + col] = acc[mi][ni][j] + bvv;
      }
  }
}

// ---------------- launch ----------------
extern "C" void kernel_launch(void* const* d_in, const int* in_sizes, int n_in,
                              void* d_out, int out_size, void* d_ws, size_t ws_size,
                              hipStream_t stream) {
  (void)in_sizes; (void)n_in; (void)out_size; (void)ws_size;
  const float* x  = (const float*)d_in[0];
  const float* y  = (const float*)d_in[1];
  const float* Wq = (const float*)d_in[2];
  const float* bq = (const float*)d_in[3];
  const float* Wk = (const float*)d_in[4];
  const float* bk = (const float*)d_in[5];
  const float* Wv = (const float*)d_in[6];
  const float* bv = (const float*)d_in[7];
  const float* Wo = (const float*)d_in[8];
  const float* bo = (const float*)d_in[9];

  char* ws = (char*)d_ws;
  half_t* S    = (half_t*)(ws + WS_S);
  half_t* Wqc  = (half_t*)(ws + WS_WQC);
  half_t* Wot  = (half_t*)(ws + WS_WOT);
  half_t* Wkvt = (half_t*)(ws + WS_WKVT);
  half_t* yh   = (half_t*)(ws + WS_YH);
  half_t* kvb  = (half_t*)(ws + WS_KV);
  float*  bkv  = (float*)(ws + WS_BKV);
  half_t* Bt1  = (half_t*)(ws + WS_BT1);
  half_t* Bt2  = (half_t*)(ws + WS_BT2);
  float*  c1   = (float*)(ws + WS_C1);

  dim3 tb(32, 8);
  cast_f32_f16<<<512, 256, 0, stream>>>(Wq, Wqc);
  transpose_f32f16<<<dim3(32, 32), tb, 0, stream>>>(Wo, Wot, 1024, 1024);
  transpose_f32f16<<<dim3(32, 24), tb, 0, stream>>>(Wk, Wkvt, 768, 1024);
  transpose_f32f16<<<dim3(32, 24), tb, 0, stream>>>(Wv, Wkvt + (size_t)1024*768, 768, 1024);
  convert_pad_y<<<BATCH*SKV_PAD*D_CROSS/256, 256, 0, stream>>>(y, yh);
  concat_bias<<<2*D_EMBED/256, 256, 0, stream>>>(bk, bv, bkv);

  gemm_kv<<<dim3(16, 5), 256, 0, stream>>>(yh, Wkvt, bkv, kvb, BATCH*SKV_PAD, 2048, 768);

  c1_build<<<BATCH*NKV/256, 256, 0, stream>>>(kvb, bq, c1);
  w1_build<<<BATCH*N_HEADS, 256, 0, stream>>>(kvb, Wqc, Bt1);
  w2_build<<<BATCH*N_HEADS, 256, 0, stream>>>(kvb, Wot, Bt2);

  // S = x @ W1[b] + c1[b]  (stores S A-swizzled)
  gemm_s<5><<<1280, 256, 0, stream>>>(x, Bt1, c1, S, M_Q, NKV, 1024);

  // P = softmax(S), in place (swizzle-aware)
  softmax_inplace<<<M_Q*N_HEADS/256, 256, 0, stream>>>(S);

  // out = P @ W2[b] + bo : 8-phase 256^2
  gemm8p_out<<<512, 512, 0, stream>>>(S, Bt2, bo, (float*)d_out);
}